// Round 9
// baseline (2215.299 us; speedup 1.0000x reference)
//
#include <hip/hip_runtime.h>

#define N_NODESC 100000
#define N_EDGESC 1600000
#define NB_BUCKETS 391      // ceil(100000/256)
#define BUCKET_CAP 5120     // mean 4092, sigma 64 -> +16 sigma headroom (fixed graph)
#define CHUNK_A 4096
// IN_C = 128, HID_C = 128, OUT_C = 64

typedef __attribute__((ext_vector_type(4))) float floatx4;
typedef __attribute__((ext_vector_type(8))) short shortx8;

// ---------------- bf16 helpers ----------------
__device__ __forceinline__ unsigned short f32_to_bf16_rne(float f) {
    unsigned int u = __float_as_uint(f);
    unsigned int r = u + 0x7fffu + ((u >> 16) & 1u);
    return (unsigned short)(r >> 16);
}
__device__ __forceinline__ float bf16_to_f32(unsigned short h) {
    return __uint_as_float(((unsigned int)h) << 16);
}
__device__ __forceinline__ float bflo(unsigned int u) { return __uint_as_float(u << 16); }
__device__ __forceinline__ float bfhi(unsigned int u) { return __uint_as_float(u & 0xffff0000u); }
__device__ __forceinline__ unsigned int pack2bf(float a, float b) {
    return ((unsigned int)f32_to_bf16_rne(b) << 16) | (unsigned int)f32_to_bf16_rne(a);
}
// workgroup-scope relaxed f32 add -> hardware ds_add_f32 on gfx950
__device__ __forceinline__ void lds_fadd(float* p, float v) {
    __hip_atomic_fetch_add(p, v, __ATOMIC_RELAXED, __HIP_MEMORY_SCOPE_WORKGROUP);
}

// ---------------- fused W pre-pack (W1 + W2) + fixed-stride gcur init ----------
__global__ __launch_bounds__(256) void k_wfrag_all(const float* __restrict__ W1,
        const float* __restrict__ W2,
        unsigned short* __restrict__ w1hi, unsigned short* __restrict__ w1lo,
        unsigned short* __restrict__ w2hi, unsigned short* __restrict__ w2lo,
        int* __restrict__ gcur) {
    int t = threadIdx.x;
    if (blockIdx.x == 0)
        for (int i = t; i < NB_BUCKETS; i += 256) gcur[i] = i * BUCKET_CAP;
    int idx = blockIdx.x * 256 + t;
    float f;
    int k, col, C, o;
    unsigned short *phi, *plo;
    if (idx < 16384) {
        k = idx >> 7; col = idx & 127; C = 8;
        f = W1[idx]; phi = w1hi; plo = w1lo;
    } else {
        int idx2 = idx - 16384;
        k = idx2 >> 6; col = idx2 & 63; C = 4;
        f = W2[idx2]; phi = w2hi; plo = w2lo;
    }
    unsigned short hi = f32_to_bf16_rne(f);
    unsigned short lo = f32_to_bf16_rne(f - bf16_to_f32(hi));
    int kc = k >> 5, q = (k >> 3) & 3, j = k & 7;
    int c = col >> 4, n = col & 15;
    o = (((kc * C + c) * 4 + q) * 16 + n) * 8 + j;
    phi[o] = hi; plo[o] = lo;
}

// ---------------- phase A: bucket edges by dst>>8 into fixed-stride tmp windows.
// 1024-thread blocks, CHUNK_A=4096 -> 391 blocks (r2/r3-proven). -----------------
__global__ __launch_bounds__(1024) void k_bucket(const int* __restrict__ src,
        const int* __restrict__ dst, int* __restrict__ gcur,
        unsigned int* __restrict__ tmp) {
    __shared__ int hist[NB_BUCKETS];
    int t = threadIdx.x;
    for (int i = t; i < NB_BUCKETS; i += 1024) hist[i] = 0;
    __syncthreads();
    int base = blockIdx.x * CHUNK_A;
    int end = min(base + CHUNK_A, N_EDGESC);
    for (int e = base + t; e < end; e += 1024)
        atomicAdd(&hist[dst[e] >> 8], 1);
    __syncthreads();
    for (int i = t; i < NB_BUCKETS; i += 1024) {
        int c = hist[i];
        hist[i] = (c > 0) ? atomicAdd(&gcur[i], c) : 0;
    }
    __syncthreads();
    for (int e = base + t; e < end; e += 1024) {
        int d = dst[e];
        int pos = atomicAdd(&hist[d >> 8], 1);
        tmp[pos] = ((unsigned int)src[e] << 8) | (unsigned int)(d & 255);
    }
}

// ---------------- per-bucket degree histogram -> dinv only (replaces k_place;
// no CSR/swsrc needed anymore — aggregation reads tmp directly). ----------------
__global__ __launch_bounds__(1024) void k_count(const unsigned int* __restrict__ tmp,
        const int* __restrict__ gcur, float* __restrict__ dinv) {
    __shared__ int hist[256];
    int b = blockIdx.x, t = threadIdx.x;
    if (t < 256) hist[t] = 0;
    __syncthreads();
    int start = b * BUCKET_CAP;
    int end = gcur[b];
    for (int i = start + t; i < end; i += 1024)
        atomicAdd(&hist[tmp[i] & 255u], 1);
    __syncthreads();
    if (t < 256) {
        int node = (b << 8) + t;
        if (node < N_NODESC) dinv[node] = rsqrtf((float)hist[t] + 1.0f);
    }
}

// ---------------- GEMM via MFMA: H[N,NOUT](bf16) = (A[N,128] @ W) * dinv[row].
// r3-proven: epilogue LDS tile is WAVE-PRIVATE -> wave_barrier only. ------------
template<int NOUT, int AFP32>
__global__ __launch_bounds__(256) void k_gemm_mfma(const void* __restrict__ Xv,
        const unsigned short* __restrict__ whi, const unsigned short* __restrict__ wlo,
        const float* __restrict__ dinv, unsigned short* __restrict__ H) {
    constexpr int C = NOUT / 16;
    constexpr int PITCH = NOUT + 4;
    __shared__ __align__(16) float etile[4][16][PITCH];
    int wv = threadIdx.x >> 6, lane = threadIdx.x & 63;
    int n16 = lane & 15, q = lane >> 4;
    int rowBase = blockIdx.x * 128 + wv * 32;
    floatx4 acc[2][C];
#pragma unroll
    for (int m = 0; m < 2; ++m)
#pragma unroll
        for (int c = 0; c < C; ++c) acc[m][c] = (floatx4){0.f, 0.f, 0.f, 0.f};

    const shortx8* whi8 = (const shortx8*)whi;
    const shortx8* wlo8 = (const shortx8*)wlo;

    for (int kc = 0; kc < 4; ++kc) {
        shortx8 ahi[2], alo[2];
#pragma unroll
        for (int m = 0; m < 2; ++m) {
            int r = rowBase + m * 16 + n16;
            if (r >= N_NODESC) r = N_NODESC - 1;
            if (AFP32) {
                const float* xp = &((const float*)Xv)[(size_t)r * 128 + kc * 32 + q * 8];
                floatx4 x0 = *(const floatx4*)xp;
                floatx4 x1 = *(const floatx4*)(xp + 4);
#pragma unroll
                for (int jj = 0; jj < 4; ++jj) {
                    unsigned short h0 = f32_to_bf16_rne(x0[jj]);
                    ahi[m][jj] = (short)h0;
                    alo[m][jj] = (short)f32_to_bf16_rne(x0[jj] - bf16_to_f32(h0));
                    unsigned short h1 = f32_to_bf16_rne(x1[jj]);
                    ahi[m][jj + 4] = (short)h1;
                    alo[m][jj + 4] = (short)f32_to_bf16_rne(x1[jj] - bf16_to_f32(h1));
                }
            } else {
                const unsigned short* xp = &((const unsigned short*)Xv)[(size_t)r * 128 + kc * 32 + q * 8];
                ahi[m] = *(const shortx8*)xp;
            }
        }
#pragma unroll
        for (int c = 0; c < C; ++c) {
            int fo = (kc * C + c) * 64 + lane;
            shortx8 bhi = whi8[fo];
            shortx8 blo = wlo8[fo];
#pragma unroll
            for (int m = 0; m < 2; ++m) {
                acc[m][c] = __builtin_amdgcn_mfma_f32_16x16x32_bf16(ahi[m], bhi, acc[m][c], 0, 0, 0);
                if (AFP32)
                    acc[m][c] = __builtin_amdgcn_mfma_f32_16x16x32_bf16(alo[m], bhi, acc[m][c], 0, 0, 0);
                acc[m][c] = __builtin_amdgcn_mfma_f32_16x16x32_bf16(ahi[m], blo, acc[m][c], 0, 0, 0);
            }
        }
    }
    constexpr int CPL = NOUT / 4;
#pragma unroll
    for (int m = 0; m < 2; ++m) {
        __builtin_amdgcn_wave_barrier();
#pragma unroll
        for (int c = 0; c < C; ++c)
#pragma unroll
            for (int reg = 0; reg < 4; ++reg)
                etile[wv][q * 4 + reg][c * 16 + n16] = acc[m][c][reg];
        asm volatile("s_waitcnt lgkmcnt(0)" ::: "memory");
        __builtin_amdgcn_wave_barrier();
        int row = lane >> 2, cb = lane & 3;
        int r = rowBase + m * 16 + row;
        if (r < N_NODESC) {
            float dv = dinv[r];
            unsigned int po[CPL / 2];
#pragma unroll
            for (int i = 0; i < CPL / 4; ++i) {
                floatx4 v = *(const floatx4*)&etile[wv][row][cb * CPL + i * 4];
                po[i * 2 + 0] = pack2bf(v[0] * dv, v[1] * dv);
                po[i * 2 + 1] = pack2bf(v[2] * dv, v[3] * dv);
            }
            unsigned int* op = (unsigned int*)&H[(size_t)r * NOUT + cb * CPL];
#pragma unroll
            for (int i = 0; i < CPL / 8; ++i)
                *(uint4*)(op + i * 4) = *(uint4*)&po[i * 4];
        }
        asm volatile("s_waitcnt lgkmcnt(0)" ::: "memory");
        __builtin_amdgcn_wave_barrier();
    }
}

// ---------------- layer-1 aggregation from tmp: block = bucket (256 nodes),
// fp32 LDS accumulators acc[node][c][l16] (pad 17 -> bank (8d+17c+l16)%32,
// ~2 lanes/bank = free). One visit per edge: 16 lanes x 16B = full 256B row
// (the proven agg128 access shape), 8 ds_add_f32 per lane, unroll 2 for MLP.
// Finalize in-block: e = dv*(acc + H1self) + b1, relu, pack bf16. --------------
__global__ __launch_bounds__(1024) void k_aggL1(const unsigned short* __restrict__ H1,
        const unsigned int* __restrict__ tmp, const int* __restrict__ gcur,
        const float* __restrict__ dinv, const float* __restrict__ b1,
        unsigned short* __restrict__ H1a) {
    __shared__ float acc[256][8][17];   // 139,264 B
    int b = blockIdx.x, t = threadIdx.x;
    float* af = &acc[0][0][0];
    for (int i = t; i < 256 * 8 * 17; i += 1024) af[i] = 0.f;
    __syncthreads();
    int start = b * BUCKET_CAP;
    int end = gcur[b];
    int l16 = t & 15, eoff = t >> 4;    // 64 edges in flight per pass
    int e = start + eoff;
    for (; e + 64 < end; e += 128) {
        unsigned int v0 = tmp[e];
        unsigned int v1 = tmp[e + 64];
        int s0 = v0 >> 8, d0 = (int)(v0 & 255u);
        int s1 = v1 >> 8, d1 = (int)(v1 & 255u);
        uint4 h0 = *(const uint4*)(H1 + (size_t)s0 * 128 + l16 * 8);
        uint4 h1 = *(const uint4*)(H1 + (size_t)s1 * 128 + l16 * 8);
        float* a0 = &acc[d0][0][l16];
        float* a1 = &acc[d1][0][l16];
        lds_fadd(a0 + 0 * 17, bflo(h0.x)); lds_fadd(a0 + 1 * 17, bfhi(h0.x));
        lds_fadd(a0 + 2 * 17, bflo(h0.y)); lds_fadd(a0 + 3 * 17, bfhi(h0.y));
        lds_fadd(a0 + 4 * 17, bflo(h0.z)); lds_fadd(a0 + 5 * 17, bfhi(h0.z));
        lds_fadd(a0 + 6 * 17, bflo(h0.w)); lds_fadd(a0 + 7 * 17, bfhi(h0.w));
        lds_fadd(a1 + 0 * 17, bflo(h1.x)); lds_fadd(a1 + 1 * 17, bfhi(h1.x));
        lds_fadd(a1 + 2 * 17, bflo(h1.y)); lds_fadd(a1 + 3 * 17, bfhi(h1.y));
        lds_fadd(a1 + 4 * 17, bflo(h1.z)); lds_fadd(a1 + 5 * 17, bfhi(h1.z));
        lds_fadd(a1 + 6 * 17, bflo(h1.w)); lds_fadd(a1 + 7 * 17, bfhi(h1.w));
    }
    if (e < end) {
        unsigned int v0 = tmp[e];
        int s0 = v0 >> 8, d0 = (int)(v0 & 255u);
        uint4 h0 = *(const uint4*)(H1 + (size_t)s0 * 128 + l16 * 8);
        float* a0 = &acc[d0][0][l16];
        lds_fadd(a0 + 0 * 17, bflo(h0.x)); lds_fadd(a0 + 1 * 17, bfhi(h0.x));
        lds_fadd(a0 + 2 * 17, bflo(h0.y)); lds_fadd(a0 + 3 * 17, bfhi(h0.y));
        lds_fadd(a0 + 4 * 17, bflo(h0.z)); lds_fadd(a0 + 5 * 17, bfhi(h0.z));
        lds_fadd(a0 + 6 * 17, bflo(h0.w)); lds_fadd(a0 + 7 * 17, bfhi(h0.w));
    }
    __syncthreads();
    // finalize: thread t -> node n = t>>2, quarter q4 = t&3 (channels q4*32..+31)
    int n = t >> 2, q4 = t & 3;
    int node = (b << 8) + n;
    if (node < N_NODESC) {
        float dv = dinv[node];
        const unsigned short* sp = H1 + (size_t)node * 128 + q4 * 32;
        unsigned int po[16];
#pragma unroll
        for (int k = 0; k < 4; ++k) {
            int l = q4 * 4 + k;                    // chs l*8 .. l*8+7
            uint4 sv = *(const uint4*)(sp + k * 8);
            floatx4 bb0 = *(const floatx4*)&b1[l * 8];
            floatx4 bb1 = *(const floatx4*)&b1[l * 8 + 4];
            float e0 = dv * (acc[n][0][l] + bflo(sv.x)) + bb0[0];
            float e1 = dv * (acc[n][1][l] + bfhi(sv.x)) + bb0[1];
            float e2 = dv * (acc[n][2][l] + bflo(sv.y)) + bb0[2];
            float e3 = dv * (acc[n][3][l] + bfhi(sv.y)) + bb0[3];
            float e4 = dv * (acc[n][4][l] + bflo(sv.z)) + bb1[0];
            float e5 = dv * (acc[n][5][l] + bfhi(sv.z)) + bb1[1];
            float e6 = dv * (acc[n][6][l] + bflo(sv.w)) + bb1[2];
            float e7 = dv * (acc[n][7][l] + bfhi(sv.w)) + bb1[3];
            po[k * 4 + 0] = pack2bf(fmaxf(e0, 0.f), fmaxf(e1, 0.f));
            po[k * 4 + 1] = pack2bf(fmaxf(e2, 0.f), fmaxf(e3, 0.f));
            po[k * 4 + 2] = pack2bf(fmaxf(e4, 0.f), fmaxf(e5, 0.f));
            po[k * 4 + 3] = pack2bf(fmaxf(e6, 0.f), fmaxf(e7, 0.f));
        }
        unsigned int* op = (unsigned int*)&H1a[(size_t)node * 128 + q4 * 32];
#pragma unroll
        for (int i = 0; i < 4; ++i)
            *(uint4*)(op + i * 4) = *(uint4*)&po[i * 4];
    }
}

// ---------------- layer-2 aggregation from tmp: same structure, 64 channels.
// acc[node][c 0..3][l16 pad 17] = 69,632 B -> 2 blocks/CU. 16 lanes x 8B = full
// 128B row per edge visit. Output fp32 + b2, no relu. --------------------------
__global__ __launch_bounds__(1024) void k_aggL2(const unsigned short* __restrict__ H2,
        const unsigned int* __restrict__ tmp, const int* __restrict__ gcur,
        const float* __restrict__ dinv, const float* __restrict__ b2,
        float* __restrict__ out) {
    __shared__ float acc[256][4][17];   // 69,632 B
    int b = blockIdx.x, t = threadIdx.x;
    float* af = &acc[0][0][0];
    for (int i = t; i < 256 * 4 * 17; i += 1024) af[i] = 0.f;
    __syncthreads();
    int start = b * BUCKET_CAP;
    int end = gcur[b];
    int l16 = t & 15, eoff = t >> 4;
    int e = start + eoff;
    for (; e + 64 < end; e += 128) {
        unsigned int v0 = tmp[e];
        unsigned int v1 = tmp[e + 64];
        int s0 = v0 >> 8, d0 = (int)(v0 & 255u);
        int s1 = v1 >> 8, d1 = (int)(v1 & 255u);
        uint2 h0 = *(const uint2*)(H2 + (size_t)s0 * 64 + l16 * 4);
        uint2 h1 = *(const uint2*)(H2 + (size_t)s1 * 64 + l16 * 4);
        float* a0 = &acc[d0][0][l16];
        float* a1 = &acc[d1][0][l16];
        lds_fadd(a0 + 0 * 17, bflo(h0.x)); lds_fadd(a0 + 1 * 17, bfhi(h0.x));
        lds_fadd(a0 + 2 * 17, bflo(h0.y)); lds_fadd(a0 + 3 * 17, bfhi(h0.y));
        lds_fadd(a1 + 0 * 17, bflo(h1.x)); lds_fadd(a1 + 1 * 17, bfhi(h1.x));
        lds_fadd(a1 + 2 * 17, bflo(h1.y)); lds_fadd(a1 + 3 * 17, bfhi(h1.y));
    }
    if (e < end) {
        unsigned int v0 = tmp[e];
        int s0 = v0 >> 8, d0 = (int)(v0 & 255u);
        uint2 h0 = *(const uint2*)(H2 + (size_t)s0 * 64 + l16 * 4);
        float* a0 = &acc[d0][0][l16];
        lds_fadd(a0 + 0 * 17, bflo(h0.x)); lds_fadd(a0 + 1 * 17, bfhi(h0.x));
        lds_fadd(a0 + 2 * 17, bflo(h0.y)); lds_fadd(a0 + 3 * 17, bfhi(h0.y));
    }
    __syncthreads();
    // finalize: thread t -> node n = t>>2, q4 = t&3 (channels q4*16..+15)
    int n = t >> 2, q4 = t & 3;
    int node = (b << 8) + n;
    if (node < N_NODESC) {
        float dv = dinv[node];
        const unsigned short* sp = H2 + (size_t)node * 64 + q4 * 16;
#pragma unroll
        for (int k = 0; k < 4; ++k) {
            int l = q4 * 4 + k;                    // chs l*4 .. l*4+3
            uint2 sv = *(const uint2*)(sp + k * 4);
            floatx4 bb = *(const floatx4*)&b2[l * 4];
            floatx4 o;
            o[0] = dv * (acc[n][0][l] + bflo(sv.x)) + bb[0];
            o[1] = dv * (acc[n][1][l] + bfhi(sv.x)) + bb[1];
            o[2] = dv * (acc[n][2][l] + bflo(sv.y)) + bb[2];
            o[3] = dv * (acc[n][3][l] + bfhi(sv.y)) + bb[3];
            *(floatx4*)&out[(size_t)node * 64 + q4 * 16 + k * 4] = o;
        }
    }
}

extern "C" void kernel_launch(void* const* d_in, const int* in_sizes, int n_in,
                              void* d_out, int out_size, void* d_ws, size_t ws_size,
                              hipStream_t stream) {
    const float* x  = (const float*)d_in[0];
    const int*   ei = (const int*)d_in[1];
    const float* W1 = (const float*)d_in[2];
    const float* b1 = (const float*)d_in[3];
    const float* W2 = (const float*)d_in[4];
    const float* b2 = (const float*)d_in[5];
    float* out = (float*)d_out;
    const int* src = ei;
    const int* dst = ei + N_EDGESC;

    char* ws = (char*)d_ws;
    size_t off = 0;
    auto alloc = [&](size_t bytes) -> void* {
        off = (off + 255) & ~(size_t)255;
        void* p = ws + off;
        off += bytes;
        return p;
    };
    const size_t CSR_SLOTS = (size_t)NB_BUCKETS * BUCKET_CAP;   // 2,001,920
    float* dinv    = (float*)alloc((size_t)N_NODESC * 4);
    int*   gcur    = (int*)  alloc(NB_BUCKETS * 4);
    unsigned int* tmp = (unsigned int*)alloc(CSR_SLOTS * 4);
    unsigned short* w1hi = (unsigned short*)alloc(128 * 128 * 2);
    unsigned short* w1lo = (unsigned short*)alloc(128 * 128 * 2);
    unsigned short* w2hi = (unsigned short*)alloc(128 * 64 * 2);
    unsigned short* w2lo = (unsigned short*)alloc(128 * 64 * 2);
    unsigned short* h1b  = (unsigned short*)alloc((size_t)N_NODESC * 128 * 2);  // x@W1 * dinv
    unsigned short* h1a  = (unsigned short*)alloc((size_t)N_NODESC * 128 * 2);  // relu'd layer-1 out
    unsigned short* h2b  = (unsigned short*)alloc((size_t)N_NODESC * 64 * 2);   // h1a@W2 * dinv

    const int nbGemm = (N_NODESC + 127) / 128;              // 782
    const int nbBkt  = (N_EDGESC + CHUNK_A - 1) / CHUNK_A;  // 391

    k_wfrag_all<<<(16384 + 8192) / 256, 256, 0, stream>>>(W1, W2, w1hi, w1lo, w2hi, w2lo, gcur);
    k_bucket<<<nbBkt, 1024, 0, stream>>>(src, dst, gcur, tmp);
    k_count<<<NB_BUCKETS, 1024, 0, stream>>>(tmp, gcur, dinv);

    k_gemm_mfma<128, 1><<<nbGemm, 256, 0, stream>>>(x, w1hi, w1lo, dinv, h1b);
    k_aggL1<<<NB_BUCKETS, 1024, 0, stream>>>(h1b, tmp, gcur, dinv, b1, h1a);
    k_gemm_mfma<64, 0><<<nbGemm, 256, 0, stream>>>(h1a, w2hi, w2lo, dinv, h2b);
    k_aggL2<<<NB_BUCKETS, 1024, 0, stream>>>(h2b, tmp, gcur, dinv, b2, out);
}

// Round 10
// 275.458 us; speedup vs baseline: 8.0422x; 8.0422x over previous
//
#include <hip/hip_runtime.h>

#define N_NODESC 100000
#define N_EDGESC 1600000
#define NB_BUCKETS 391      // ceil(100000/256)
#define BUCKET_CAP 5120     // mean 4092, sigma 64 -> +16 sigma headroom (fixed graph)
#define CHUNK_A 4096
// IN_C = 128, HID_C = 128, OUT_C = 64

typedef __attribute__((ext_vector_type(4))) float floatx4;
typedef __attribute__((ext_vector_type(8))) short shortx8;

// ---------------- bf16 helpers ----------------
__device__ __forceinline__ unsigned short f32_to_bf16_rne(float f) {
    unsigned int u = __float_as_uint(f);
    unsigned int r = u + 0x7fffu + ((u >> 16) & 1u);
    return (unsigned short)(r >> 16);
}
__device__ __forceinline__ float bf16_to_f32(unsigned short h) {
    return __uint_as_float(((unsigned int)h) << 16);
}
__device__ __forceinline__ float bflo(unsigned int u) { return __uint_as_float(u << 16); }
__device__ __forceinline__ float bfhi(unsigned int u) { return __uint_as_float(u & 0xffff0000u); }
__device__ __forceinline__ unsigned int pack2bf(float a, float b) {
    return ((unsigned int)f32_to_bf16_rne(b) << 16) | (unsigned int)f32_to_bf16_rne(a);
}

// ---------------- fused W pre-pack (W1 + W2) + fixed-stride gcur init ----------
__global__ __launch_bounds__(256) void k_wfrag_all(const float* __restrict__ W1,
        const float* __restrict__ W2,
        unsigned short* __restrict__ w1hi, unsigned short* __restrict__ w1lo,
        unsigned short* __restrict__ w2hi, unsigned short* __restrict__ w2lo,
        int* __restrict__ gcur) {
    int t = threadIdx.x;
    if (blockIdx.x == 0)
        for (int i = t; i < NB_BUCKETS; i += 256) gcur[i] = i * BUCKET_CAP;
    int idx = blockIdx.x * 256 + t;
    float f;
    int k, col, C, o;
    unsigned short *phi, *plo;
    if (idx < 16384) {
        k = idx >> 7; col = idx & 127; C = 8;
        f = W1[idx]; phi = w1hi; plo = w1lo;
    } else {
        int idx2 = idx - 16384;
        k = idx2 >> 6; col = idx2 & 63; C = 4;
        f = W2[idx2]; phi = w2hi; plo = w2lo;
    }
    unsigned short hi = f32_to_bf16_rne(f);
    unsigned short lo = f32_to_bf16_rne(f - bf16_to_f32(hi));
    int kc = k >> 5, q = (k >> 3) & 3, j = k & 7;
    int c = col >> 4, n = col & 15;
    o = (((kc * C + c) * 4 + q) * 16 + n) * 8 + j;
    phi[o] = hi; plo[o] = lo;
}

// ---------------- phase A: bucket edges by dst>>8 into fixed-stride tmp windows.
// 1024-thread blocks, CHUNK_A=4096 -> 391 blocks. Edges register-cached during
// the histogram pass (<=4/thread, statically indexed) so the scatter pass does
// zero global re-reads. ---------------------------------------------------------
__global__ __launch_bounds__(1024) void k_bucket(const int* __restrict__ src,
        const int* __restrict__ dst, int* __restrict__ gcur,
        unsigned int* __restrict__ tmp) {
    __shared__ int hist[NB_BUCKETS];
    int t = threadIdx.x;
    for (int i = t; i < NB_BUCKETS; i += 1024) hist[i] = 0;
    __syncthreads();
    int base = blockIdx.x * CHUNK_A;
    int end = min(base + CHUNK_A, N_EDGESC);
    unsigned int cv[4];
    int cb[4];
#pragma unroll
    for (int k = 0; k < 4; ++k) {
        int e = base + t + k * 1024;
        cb[k] = -1;
        if (e < end) {
            int s = src[e], d = dst[e];
            cv[k] = ((unsigned int)s << 8) | (unsigned int)(d & 255);
            cb[k] = d >> 8;
            atomicAdd(&hist[cb[k]], 1);
        }
    }
    __syncthreads();
    for (int i = t; i < NB_BUCKETS; i += 1024) {
        int c = hist[i];
        hist[i] = (c > 0) ? atomicAdd(&gcur[i], c) : 0;
    }
    __syncthreads();
#pragma unroll
    for (int k = 0; k < 4; ++k) {
        if (cb[k] >= 0) {
            int pos = atomicAdd(&hist[cb[k]], 1);
            tmp[pos] = cv[k];
        }
    }
}

// ---------------- phase B: per-bucket deg/row_ptr/dinv + exact CSR placement.
// Single global pass: bucket window staged in 20KB LDS; histogram, scan, and
// scatter all read from LDS (r3-proven). ----------------------------------------
__global__ __launch_bounds__(1024) void k_place(const unsigned int* __restrict__ tmp,
        const int* __restrict__ gcur,
        int* __restrict__ swsrc, int* __restrict__ deg,
        int* __restrict__ row_ptr, float* __restrict__ dinv) {
    __shared__ unsigned int eb[BUCKET_CAP];
    __shared__ int hist[256], scan[256], lcur[256];
    int b = blockIdx.x, t = threadIdx.x;
    int start = b * BUCKET_CAP;
    int cnt = gcur[b] - start;   // after phase A, gcur[b] == start + count(b)
    if (t < 256) hist[t] = 0;
    for (int i = t; i < cnt; i += 1024) eb[i] = tmp[start + i];
    __syncthreads();
    for (int i = t; i < cnt; i += 1024)
        atomicAdd(&hist[eb[i] & 255u], 1);
    __syncthreads();
    int own = (t < 256) ? hist[t] : 0;
    if (t < 256) scan[t] = own;
    __syncthreads();
    for (int off = 1; off < 256; off <<= 1) {
        int add = (t >= off && t < 256) ? scan[t - off] : 0;
        __syncthreads();
        if (t < 256) scan[t] += add;
        __syncthreads();
    }
    if (t < 256) {
        int rp = start + scan[t] - own;
        lcur[t] = rp;
        int node = (b << 8) + t;
        if (node < N_NODESC) {
            deg[node] = own;
            row_ptr[node] = rp;
            dinv[node] = rsqrtf((float)own + 1.0f);
        }
    }
    __syncthreads();
    for (int i = t; i < cnt; i += 1024) {
        unsigned int v = eb[i];
        int pos = atomicAdd(&lcur[v & 255u], 1);
        swsrc[pos] = (int)(v >> 8);
    }
}

// ---------------- GEMM via MFMA: H[N,NOUT](bf16) = (A[N,128] @ W) * dinv[row].
// Epilogue LDS tile is WAVE-PRIVATE (etile[wv]) -> no __syncthreads; only
// intra-wave LDS ordering (wave_barrier + lgkmcnt drain) is required. ----------
template<int NOUT, int AFP32>
__global__ __launch_bounds__(256) void k_gemm_mfma(const void* __restrict__ Xv,
        const unsigned short* __restrict__ whi, const unsigned short* __restrict__ wlo,
        const float* __restrict__ dinv, unsigned short* __restrict__ H) {
    constexpr int C = NOUT / 16;
    constexpr int PITCH = NOUT + 4;
    __shared__ __align__(16) float etile[4][16][PITCH];
    int wv = threadIdx.x >> 6, lane = threadIdx.x & 63;
    int n16 = lane & 15, q = lane >> 4;
    int rowBase = blockIdx.x * 128 + wv * 32;
    floatx4 acc[2][C];
#pragma unroll
    for (int m = 0; m < 2; ++m)
#pragma unroll
        for (int c = 0; c < C; ++c) acc[m][c] = (floatx4){0.f, 0.f, 0.f, 0.f};

    const shortx8* whi8 = (const shortx8*)whi;
    const shortx8* wlo8 = (const shortx8*)wlo;

    for (int kc = 0; kc < 4; ++kc) {
        shortx8 ahi[2], alo[2];
#pragma unroll
        for (int m = 0; m < 2; ++m) {
            int r = rowBase + m * 16 + n16;
            if (r >= N_NODESC) r = N_NODESC - 1;
            if (AFP32) {
                const float* xp = &((const float*)Xv)[(size_t)r * 128 + kc * 32 + q * 8];
                floatx4 x0 = *(const floatx4*)xp;
                floatx4 x1 = *(const floatx4*)(xp + 4);
#pragma unroll
                for (int jj = 0; jj < 4; ++jj) {
                    unsigned short h0 = f32_to_bf16_rne(x0[jj]);
                    ahi[m][jj] = (short)h0;
                    alo[m][jj] = (short)f32_to_bf16_rne(x0[jj] - bf16_to_f32(h0));
                    unsigned short h1 = f32_to_bf16_rne(x1[jj]);
                    ahi[m][jj + 4] = (short)h1;
                    alo[m][jj + 4] = (short)f32_to_bf16_rne(x1[jj] - bf16_to_f32(h1));
                }
            } else {
                const unsigned short* xp = &((const unsigned short*)Xv)[(size_t)r * 128 + kc * 32 + q * 8];
                ahi[m] = *(const shortx8*)xp;
            }
        }
#pragma unroll
        for (int c = 0; c < C; ++c) {
            int fo = (kc * C + c) * 64 + lane;
            shortx8 bhi = whi8[fo];
            shortx8 blo = wlo8[fo];
#pragma unroll
            for (int m = 0; m < 2; ++m) {
                acc[m][c] = __builtin_amdgcn_mfma_f32_16x16x32_bf16(ahi[m], bhi, acc[m][c], 0, 0, 0);
                if (AFP32)
                    acc[m][c] = __builtin_amdgcn_mfma_f32_16x16x32_bf16(alo[m], bhi, acc[m][c], 0, 0, 0);
                acc[m][c] = __builtin_amdgcn_mfma_f32_16x16x32_bf16(ahi[m], blo, acc[m][c], 0, 0, 0);
            }
        }
    }
    constexpr int CPL = NOUT / 4;
#pragma unroll
    for (int m = 0; m < 2; ++m) {
        __builtin_amdgcn_wave_barrier();
#pragma unroll
        for (int c = 0; c < C; ++c)
#pragma unroll
            for (int reg = 0; reg < 4; ++reg)
                etile[wv][q * 4 + reg][c * 16 + n16] = acc[m][c][reg];
        asm volatile("s_waitcnt lgkmcnt(0)" ::: "memory");
        __builtin_amdgcn_wave_barrier();
        int row = lane >> 2, cb = lane & 3;
        int r = rowBase + m * 16 + row;
        if (r < N_NODESC) {
            float dv = dinv[r];
            unsigned int po[CPL / 2];
#pragma unroll
            for (int i = 0; i < CPL / 4; ++i) {
                floatx4 v = *(const floatx4*)&etile[wv][row][cb * CPL + i * 4];
                po[i * 2 + 0] = pack2bf(v[0] * dv, v[1] * dv);
                po[i * 2 + 1] = pack2bf(v[2] * dv, v[3] * dv);
            }
            unsigned int* op = (unsigned int*)&H[(size_t)r * NOUT + cb * CPL];
#pragma unroll
            for (int i = 0; i < CPL / 8; ++i)
                *(uint4*)(op + i * 4) = *(uint4*)&po[i * 4];
        }
        asm volatile("s_waitcnt lgkmcnt(0)" ::: "memory");
        __builtin_amdgcn_wave_barrier();
    }
}

// ---------------- FUSED: aggregation d=128 (layer-1 agg of prescaled H1, +b1,
// relu) + layer-2 GEMM (128->64, W2 hi/lo, *dinv[row]) -> H2 bf16. r3-proven:
// block = 16 nodes, 4 waves x 4 sequential nodes (gather loop = proven agg128
// shape), bf16 rows staged in 4KB XOR-swizzled LDS, per-wave 16-col MFMA slice. --
__global__ __launch_bounds__(256) void k_agg_gemm(const unsigned short* __restrict__ Hb,
        const int* __restrict__ swsrc, const int* __restrict__ row_ptr,
        const int* __restrict__ deg, const float* __restrict__ dinv,
        const float* __restrict__ bias,
        const unsigned short* __restrict__ w2hi, const unsigned short* __restrict__ w2lo,
        unsigned short* __restrict__ H2) {
    __shared__ __align__(16) unsigned int lds_h[16][64];   // 16 nodes x 128 bf16
    int wv = threadIdx.x >> 6, lane = threadIdx.x & 63;
    int g = lane >> 4, l16 = lane & 15;
    int nb = blockIdx.x * 16;

#pragma unroll
    for (int i = 0; i < 4; ++i) {
        int nt = wv * 4 + i;
        int node = nb + nt;
        int start = row_ptr[node];
        int end = start + deg[node];
        float acc[8] = {0.f, 0.f, 0.f, 0.f, 0.f, 0.f, 0.f, 0.f};
        int j = start + g;
        for (; j + 4 < end; j += 8) {
            int s0 = swsrc[j];
            int s1 = swsrc[j + 4];
            uint4 v0 = *(const uint4*)(Hb + (size_t)s0 * 128 + l16 * 8);
            uint4 v1 = *(const uint4*)(Hb + (size_t)s1 * 128 + l16 * 8);
            acc[0] += bflo(v0.x) + bflo(v1.x);
            acc[1] += bfhi(v0.x) + bfhi(v1.x);
            acc[2] += bflo(v0.y) + bflo(v1.y);
            acc[3] += bfhi(v0.y) + bfhi(v1.y);
            acc[4] += bflo(v0.z) + bflo(v1.z);
            acc[5] += bfhi(v0.z) + bfhi(v1.z);
            acc[6] += bflo(v0.w) + bflo(v1.w);
            acc[7] += bfhi(v0.w) + bfhi(v1.w);
        }
        if (j < end) {
            int s0 = swsrc[j];
            uint4 v0 = *(const uint4*)(Hb + (size_t)s0 * 128 + l16 * 8);
            acc[0] += bflo(v0.x); acc[1] += bfhi(v0.x);
            acc[2] += bflo(v0.y); acc[3] += bfhi(v0.y);
            acc[4] += bflo(v0.z); acc[5] += bfhi(v0.z);
            acc[6] += bflo(v0.w); acc[7] += bfhi(v0.w);
        }
#pragma unroll
        for (int k = 0; k < 8; ++k) {
            acc[k] += __shfl_xor(acc[k], 16);
            acc[k] += __shfl_xor(acc[k], 32);
        }
        if (g == 0) {
            float dv = dinv[node];
            uint4 sv = *(const uint4*)(Hb + (size_t)node * 128 + l16 * 8);
            floatx4 b0 = *(const floatx4*)&bias[l16 * 8];
            floatx4 b1 = *(const floatx4*)&bias[l16 * 8 + 4];
            float o0 = dv * (acc[0] + bflo(sv.x)) + b0[0];
            float o1 = dv * (acc[1] + bfhi(sv.x)) + b0[1];
            float o2 = dv * (acc[2] + bflo(sv.y)) + b0[2];
            float o3 = dv * (acc[3] + bfhi(sv.y)) + b0[3];
            float o4 = dv * (acc[4] + bflo(sv.z)) + b1[0];
            float o5 = dv * (acc[5] + bfhi(sv.z)) + b1[1];
            float o6 = dv * (acc[6] + bflo(sv.w)) + b1[2];
            float o7 = dv * (acc[7] + bfhi(sv.w)) + b1[3];
            uint4 o;
            o.x = pack2bf(fmaxf(o0, 0.f), fmaxf(o1, 0.f));
            o.y = pack2bf(fmaxf(o2, 0.f), fmaxf(o3, 0.f));
            o.z = pack2bf(fmaxf(o4, 0.f), fmaxf(o5, 0.f));
            o.w = pack2bf(fmaxf(o6, 0.f), fmaxf(o7, 0.f));
            // swizzled LDS store: word col (l16*4) ^ ((nt&7)*4)  (16B aligned)
            int pcol = (l16 * 4) ^ ((nt & 7) * 4);
            *(uint4*)&lds_h[nt][pcol] = o;
        }
    }
    __syncthreads();

    // ---- layer-2 GEMM: wave wv computes output cols [wv*16, wv*16+16) ----
    int q = lane >> 4, n16 = lane & 15;
    floatx4 accm = (floatx4){0.f, 0.f, 0.f, 0.f};
    const shortx8* whi8 = (const shortx8*)w2hi;
    const shortx8* wlo8 = (const shortx8*)w2lo;
#pragma unroll
    for (int kc = 0; kc < 4; ++kc) {
        int pcol = (kc * 16 + q * 4) ^ ((n16 & 7) * 4);
        shortx8 ahi = *(const shortx8*)&lds_h[n16][pcol];
        int fo = (kc * 4 + wv) * 64 + lane;
        shortx8 bhi = whi8[fo];
        shortx8 blo = wlo8[fo];
        accm = __builtin_amdgcn_mfma_f32_16x16x32_bf16(ahi, bhi, accm, 0, 0, 0);
        accm = __builtin_amdgcn_mfma_f32_16x16x32_bf16(ahi, blo, accm, 0, 0, 0);
    }
    // C layout: rel col = lane&15, rel row = (lane>>4)*4 + reg
    int crow = (lane >> 4) * 4;
    int ccol = wv * 16 + n16;
#pragma unroll
    for (int reg = 0; reg < 4; ++reg) {
        int r = nb + crow + reg;
        float dv = dinv[r];
        H2[(size_t)r * 64 + ccol] = f32_to_bf16_rne(accm[reg] * dv);
    }
}

// ---------------- aggregation d=64 (bf16 in, fp32 out): wave/node, 8 groups of 8
// lanes (16B each), unroll 2 -> 16 gathers in flight. R9-exact. ----------------
__global__ __launch_bounds__(256) void k_agg64(const unsigned short* __restrict__ Hb,
        const int* __restrict__ swsrc, const int* __restrict__ row_ptr,
        const int* __restrict__ deg, const float* __restrict__ dinv,
        const float* __restrict__ bias, float* __restrict__ out) {
    int node = blockIdx.x * 4 + (threadIdx.x >> 6);
    int lane = threadIdx.x & 63;
    int g = lane >> 3, l8 = lane & 7;
    int start = row_ptr[node];
    int end = start + deg[node];
    float acc[8] = {0.f, 0.f, 0.f, 0.f, 0.f, 0.f, 0.f, 0.f};
    int j = start + g;
    for (; j + 8 < end; j += 16) {
        int s0 = swsrc[j];
        int s1 = swsrc[j + 8];
        uint4 v0 = *(const uint4*)(Hb + (size_t)s0 * 64 + l8 * 8);
        uint4 v1 = *(const uint4*)(Hb + (size_t)s1 * 64 + l8 * 8);
        acc[0] += bflo(v0.x) + bflo(v1.x);
        acc[1] += bfhi(v0.x) + bfhi(v1.x);
        acc[2] += bflo(v0.y) + bflo(v1.y);
        acc[3] += bfhi(v0.y) + bfhi(v1.y);
        acc[4] += bflo(v0.z) + bflo(v1.z);
        acc[5] += bfhi(v0.z) + bfhi(v1.z);
        acc[6] += bflo(v0.w) + bflo(v1.w);
        acc[7] += bfhi(v0.w) + bfhi(v1.w);
    }
    if (j < end) {
        int s0 = swsrc[j];
        uint4 v0 = *(const uint4*)(Hb + (size_t)s0 * 64 + l8 * 8);
        acc[0] += bflo(v0.x); acc[1] += bfhi(v0.x);
        acc[2] += bflo(v0.y); acc[3] += bfhi(v0.y);
        acc[4] += bflo(v0.z); acc[5] += bfhi(v0.z);
        acc[6] += bflo(v0.w); acc[7] += bfhi(v0.w);
    }
#pragma unroll
    for (int i = 0; i < 8; ++i) {
        acc[i] += __shfl_xor(acc[i], 8);
        acc[i] += __shfl_xor(acc[i], 16);
        acc[i] += __shfl_xor(acc[i], 32);
    }
    if (g == 0) {
        float dv = dinv[node];
        uint4 sv = *(const uint4*)(Hb + (size_t)node * 64 + l8 * 8);
        floatx4 b0 = *(const floatx4*)&bias[l8 * 8];
        floatx4 b1 = *(const floatx4*)&bias[l8 * 8 + 4];
        floatx4 o0, o1;
        o0[0] = dv * (acc[0] + bflo(sv.x)) + b0[0];
        o0[1] = dv * (acc[1] + bfhi(sv.x)) + b0[1];
        o0[2] = dv * (acc[2] + bflo(sv.y)) + b0[2];
        o0[3] = dv * (acc[3] + bfhi(sv.y)) + b0[3];
        o1[0] = dv * (acc[4] + bflo(sv.z)) + b1[0];
        o1[1] = dv * (acc[5] + bfhi(sv.z)) + b1[1];
        o1[2] = dv * (acc[6] + bflo(sv.w)) + b1[2];
        o1[3] = dv * (acc[7] + bfhi(sv.w)) + b1[3];
        *(floatx4*)&out[(size_t)node * 64 + l8 * 8] = o0;
        *(floatx4*)&out[(size_t)node * 64 + l8 * 8 + 4] = o1;
    }
}

extern "C" void kernel_launch(void* const* d_in, const int* in_sizes, int n_in,
                              void* d_out, int out_size, void* d_ws, size_t ws_size,
                              hipStream_t stream) {
    const float* x  = (const float*)d_in[0];
    const int*   ei = (const int*)d_in[1];
    const float* W1 = (const float*)d_in[2];
    const float* b1 = (const float*)d_in[3];
    const float* W2 = (const float*)d_in[4];
    const float* b2 = (const float*)d_in[5];
    float* out = (float*)d_out;
    const int* src = ei;
    const int* dst = ei + N_EDGESC;

    char* ws = (char*)d_ws;
    size_t off = 0;
    auto alloc = [&](size_t bytes) -> void* {
        off = (off + 255) & ~(size_t)255;
        void* p = ws + off;
        off += bytes;
        return p;
    };
    const size_t CSR_SLOTS = (size_t)NB_BUCKETS * BUCKET_CAP;   // 2,001,920
    int*   deg     = (int*)  alloc((size_t)N_NODESC * 4);
    float* dinv    = (float*)alloc((size_t)N_NODESC * 4);
    int*   row_ptr = (int*)  alloc((size_t)N_NODESC * 4);
    int*   gcur    = (int*)  alloc(NB_BUCKETS * 4);
    unsigned int* tmp   = (unsigned int*)alloc(CSR_SLOTS * 4);
    int*   swsrc   = (int*)  alloc(CSR_SLOTS * 4);
    unsigned short* w1hi = (unsigned short*)alloc(128 * 128 * 2);
    unsigned short* w1lo = (unsigned short*)alloc(128 * 128 * 2);
    unsigned short* w2hi = (unsigned short*)alloc(128 * 64 * 2);
    unsigned short* w2lo = (unsigned short*)alloc(128 * 64 * 2);
    unsigned short* h1b  = (unsigned short*)alloc((size_t)N_NODESC * 128 * 2);
    unsigned short* h2b  = (unsigned short*)alloc((size_t)N_NODESC * 128 * 2);
    // NOTE: h2b must NOT alias h1b — k_agg_gemm gathers from h1b while writing h2b.

    const int nbGemm = (N_NODESC + 127) / 128;              // 782
    const int nbBkt  = (N_EDGESC + CHUNK_A - 1) / CHUNK_A;  // 391

    k_wfrag_all<<<(16384 + 8192) / 256, 256, 0, stream>>>(W1, W2, w1hi, w1lo, w2hi, w2lo, gcur);
    k_bucket<<<nbBkt, 1024, 0, stream>>>(src, dst, gcur, tmp);
    k_place<<<NB_BUCKETS, 1024, 0, stream>>>(tmp, gcur, swsrc, deg, row_ptr, dinv);

    k_gemm_mfma<128, 1><<<nbGemm, 256, 0, stream>>>(x, w1hi, w1lo, dinv, h1b);
    k_agg_gemm<<<N_NODESC / 16, 256, 0, stream>>>(h1b, swsrc, row_ptr, deg, dinv, b1,
                                                  w2hi, w2lo, h2b);
    k_agg64<<<N_NODESC / 4, 256, 0, stream>>>(h2b, swsrc, row_ptr, deg, dinv, b2, out);
}